// Round 6
// baseline (456.904 us; speedup 1.0000x reference)
//
#include <hip/hip_runtime.h>
#include <math.h>

#ifndef M_PI
#define M_PI 3.14159265358979323846
#endif

// ---------------- constants ----------------
#define NSIDE 128
#define NVOX  2097152          // 128^3
#define KBINS 100
#define NFIELDS 16             // 8 pred + 8 target
#define NORMF (27.0f / 2097152.0f)   // LPIX^3 / N^3
#define FSTRIDE ((size_t)65 * 16384) // float2 elems per field (kz-major planes)

// ws layout (bytes)
#define WS_SUMS_OFF   0                       // float[16*101]
#define WS_CNT_OFF    6464                    // int[101]
#define WS_OCT_OFF    8192                    // uint8[65*65*65], kz-major: oct[c][a][b]
#define WS_TRANS_OFF  282880                  // float2[16 * FSTRIDE] = 136.3 MB

// ---------------- exact numpy binning replication (fp64) ----------------
__device__ __forceinline__ double bin_edge(int i, double start, double step, double stop) {
    if (i == 100) return stop;
    return __dadd_rn(__dmul_rn((double)i, step), start);
}

__device__ __forceinline__ void bin_params(double* start, double* step, double* stop) {
    const double inv   = 1.0 / 384.0;
    const double twopi = 2.0 * M_PI;
    double k1 = __dmul_rn(twopi, __dmul_rn(1.0, inv));
    *start = sqrt(__dadd_rn(__dadd_rn(0.0, 0.0), __dmul_rn(k1, k1)));
    double k64 = __dmul_rn(twopi, __dmul_rn(-64.0, inv));
    double s64 = __dmul_rn(k64, k64);
    *stop = sqrt(__dadd_rn(__dadd_rn(s64, s64), s64));
    *step = (*stop - *start) / 100.0;
}

__device__ int compute_bin(int ix, int iy, int iz) {
    const double inv   = 1.0 / 384.0;
    const double twopi = 2.0 * M_PI;
    double fx = (double)(ix < 64 ? ix : ix - 128);
    double fy = (double)(iy < 64 ? iy : iy - 128);
    double fz = (double)(iz < 64 ? iz : iz - 128);
    double kx = __dmul_rn(twopi, __dmul_rn(fx, inv));
    double ky = __dmul_rn(twopi, __dmul_rn(fy, inv));
    double kz = __dmul_rn(twopi, __dmul_rn(fz, inv));
    double sq = __dadd_rn(__dadd_rn(__dmul_rn(kx, kx), __dmul_rn(ky, ky)), __dmul_rn(kz, kz));
    double kmag = sqrt(sq);
    if (!(kmag > 0.0)) return 100;                   // DC -> dropped bin
    double start, step, stop;
    bin_params(&start, &step, &stop);
    double t = (kmag - start) / step;
    int c = (int)floor(t);
    if (c < -1) c = -1;
    if (c > 100) c = 100;
    while (c < 100 && kmag >= bin_edge(c + 1, start, step, stop)) ++c;
    while (c >= 0 && kmag < bin_edge(c, start, step, stop)) --c;
    if (c < 0) c = 0;
    if (c > 99) c = 99;
    return c;
}

// ---------------- radix-4 DIF FFT, in-place, output digit-reversed ----------------
#define LDS_FENCE() __asm__ volatile("s_waitcnt lgkmcnt(0)" ::: "memory")

__device__ __forceinline__ int digrev(int t) {   // slot -> frequency
    return ((t >> 5) & 3) | (((t >> 3) & 3) << 2) | (((t >> 1) & 3) << 4) | ((t & 1) << 6);
}
__device__ __forceinline__ int slot_of(int k) {  // frequency -> slot
    return ((k & 3) << 5) | (((k >> 2) & 3) << 3) | (((k >> 4) & 3) << 1) | ((k >> 6) & 1);
}

__device__ __forceinline__ float2 cmul(float2 a, float2 w) {
    return make_float2(a.x * w.x - a.y * w.y, a.x * w.y + a.y * w.x);
}
__device__ __forceinline__ float2 twid(float r) {   // e^{2*pi*i*r}, r in revolutions
    return make_float2(__builtin_amdgcn_cosf(r), __builtin_amdgcn_sinf(r));
}

__device__ __forceinline__ void r4_bf(float2* p, int e0, int h, int o, float invL) {
    float2 a0 = p[e0];
    float2 a1 = p[e0 + h];
    float2 a2 = p[e0 + 2 * h];
    float2 a3 = p[e0 + 3 * h];
    float2 s0 = make_float2(a0.x + a2.x, a0.y + a2.y);
    float2 d0 = make_float2(a0.x - a2.x, a0.y - a2.y);
    float2 s1 = make_float2(a1.x + a3.x, a1.y + a3.y);
    float2 d1 = make_float2(a1.x - a3.x, a1.y - a3.y);
    float2 b0 = make_float2(s0.x + s1.x, s0.y + s1.y);
    float2 b2 = make_float2(s0.x - s1.x, s0.y - s1.y);
    float2 b1 = make_float2(d0.x + d1.y, d0.y - d1.x);   // d0 - i*d1
    float2 b3 = make_float2(d0.x - d1.y, d0.y + d1.x);   // d0 + i*d1
    float r1 = -(float)o * invL;
    float2 w1 = twid(r1), w2 = twid(2.0f * r1), w3 = twid(3.0f * r1);
    p[e0]         = b0;
    p[e0 + h]     = cmul(b1, w1);
    p[e0 + 2 * h] = cmul(b2, w2);
    p[e0 + 3 * h] = cmul(b3, w3);
}

__device__ __forceinline__ void r2_final(float2* p, int bf) {
    int j = 4 * bf;
    float2 a0 = p[j], a1 = p[j + 1], a2 = p[j + 2], a3 = p[j + 3];
    p[j]     = make_float2(a0.x + a1.x, a0.y + a1.y);
    p[j + 1] = make_float2(a0.x - a1.x, a0.y - a1.y);
    p[j + 2] = make_float2(a2.x + a3.x, a2.y + a3.y);
    p[j + 3] = make_float2(a2.x - a3.x, a2.y - a3.y);
}

// 128-pt line FFT, 32 threads/line (bf=0..31), line owned by one wave.
__device__ __forceinline__ void fft_line(float2* p, int bf) {
    r4_bf(p, bf, 32, bf, 1.0f / 128.0f);
    LDS_FENCE();
    { int B = (bf >> 3) * 32, o = bf & 7; r4_bf(p, B + o, 8, o, 1.0f / 32.0f); }
    LDS_FENCE();
    { int B = (bf >> 1) * 8,  o = bf & 1; r4_bf(p, B + o, 2, o, 1.0f / 8.0f); }
    LDS_FENCE();
    r2_final(p, bf);
    LDS_FENCE();
}

// ---------------- kernels ----------------
__global__ __launch_bounds__(256) void k_zero(float* sums, int* counts) {
    int t = blockIdx.x * 256 + threadIdx.x;
    if (t < NFIELDS * 101) sums[t] = 0.0f;
    if (t < 101) counts[t] = 0;
}

// Octant bin table (kz-major: oct[c][a][b]) + exact weighted mode counts.
__global__ __launch_bounds__(256) void k_oct(unsigned char* __restrict__ oct,
                                             int* __restrict__ counts) {
    __shared__ int lcnt[4][104];
    int tid = threadIdx.x;
#pragma unroll
    for (int j = tid; j < 4 * 104; j += 256) ((int*)lcnt)[j] = 0;
    __syncthreads();
    int idx = blockIdx.x * 256 + tid;
    if (idx < 65 * 65 * 65) {
        int c = idx % 65;
        int r = idx / 65;
        int b = r % 65;
        int a = r / 65;
        int id = compute_bin(a, b, c);
        oct[c * 4225 + a * 65 + b] = (unsigned char)id;
        if (id < 100) {
            int w = ((a == 0 || a == 64) ? 1 : 2) *
                    ((b == 0 || b == 64) ? 1 : 2) *
                    ((c == 0 || c == 64) ? 1 : 2);
            atomicAdd(&lcnt[tid & 3][id], w);
        }
    }
    __syncthreads();
    if (tid < 101) {
        int tot = lcnt[0][tid] + lcnt[1][tid] + lcnt[2][tid] + lcnt[3][tid];
        if (tot) atomicAdd(&counts[tid], tot);
    }
}

// Pass Z: FFT along z. Block: fixed x, 32 consecutive y (16 KB contiguous read).
// Writes A[f][kz][x][y] with NATURAL kz (via slot_of), kz 0..64 only.
__global__ __launch_bounds__(1024, 8) void k_fft_z(const float* __restrict__ pred,
                                                   const float* __restrict__ target,
                                                   float2* __restrict__ A) {
    __shared__ float2 L[32][129];
    int t = threadIdx.x;
    int x  = blockIdx.x >> 2;
    int y0 = (blockIdx.x & 3) << 5;
    int f = blockIdx.y;
    const float* in = (f < 8) ? (pred + (size_t)f * NVOX)
                              : (target + (size_t)(f - 8) * NVOX);
    const float* src = in + (size_t)x * 16384 + (size_t)y0 * 128;
#pragma unroll
    for (int i = 0; i < 4; ++i) {
        int n = t + 1024 * i;
        L[n >> 7][n & 127] = make_float2(src[n], 0.0f);
    }
    __syncthreads();
    fft_line(&L[t >> 5][0], t & 31);      // wave-private pair of rows
    __syncthreads();
    float2* dst = A + (size_t)f * FSTRIDE;
#pragma unroll
    for (int i = 0; i < 3; ++i) {
        int kk = (t >> 5) + 32 * i;       // natural kz
        int dy = t & 31;
        if (kk <= 64)
            dst[(size_t)kk * 16384 + (size_t)x * 128 + y0 + dy] = L[dy][slot_of(kk)];
    }
}

// Pass Y: FFT along y, in-place per 32-row tile. Read/write 32 KB contiguous.
// Output left in SLOT order along y (digit-reversal resolved arithmetically later).
__global__ __launch_bounds__(1024, 8) void k_fft_y(float2* __restrict__ A) {
    __shared__ float2 L[32][129];
    int t = threadIdx.x;
    int kz = blockIdx.x >> 2;
    int xg = blockIdx.x & 3;
    int f = blockIdx.y;
    float2* base = A + (size_t)f * FSTRIDE + (size_t)kz * 16384 + (size_t)xg * 4096;
    const float4* s4 = (const float4*)base;
#pragma unroll
    for (int i = 0; i < 2; ++i) {
        int n = t + 1024 * i;             // 2048 float4
        float4 v = s4[n];
        int dx = n >> 6;
        int y  = (n & 63) * 2;
        L[dx][y]     = make_float2(v.x, v.y);
        L[dx][y + 1] = make_float2(v.z, v.w);
    }
    __syncthreads();
    fft_line(&L[t >> 5][0], t & 31);
    __syncthreads();
    float4* d4 = (float4*)base;
#pragma unroll
    for (int i = 0; i < 2; ++i) {
        int n = t + 1024 * i;
        int dx = n >> 6;
        int y  = (n & 63) * 2;
        float2 a = L[dx][y], b = L[dx][y + 1];
        d4[n] = make_float4(a.x, a.y, b.x, b.y);
    }
}

// Pass X: FFT along x + power + radial binning. Block: fixed kz, 32 consecutive
// y-slots. Reads 256B segments (16 lanes x float4 per x-row), transposes into LDS.
// ky = digrev(s0+ds), kx = digrev(sx) applied only in the bin lookup.
__global__ __launch_bounds__(1024, 8) void k_fft_x_bin(const float2* __restrict__ A,
                                                       const unsigned char* __restrict__ oct,
                                                       float* __restrict__ sums) {
    __shared__ float2 L[32][129];
    __shared__ float lbins[8][104];
    __shared__ unsigned char ltab[4225];
    int t = threadIdx.x;
    int kz = blockIdx.x >> 2;
    int s0 = (blockIdx.x & 3) << 5;       // y-slot group
    int f = blockIdx.y;
    const float2* base = A + (size_t)f * FSTRIDE + (size_t)kz * 16384;
    for (int j = t; j < 8 * 104; j += 1024) ((float*)lbins)[j] = 0.0f;
    for (int j = t; j < 4225; j += 1024) ltab[j] = oct[kz * 4225 + j];
#pragma unroll
    for (int i = 0; i < 2; ++i) {
        int n = t + 1024 * i;             // 2048 float4
        int x = n >> 4;
        int m = n & 15;
        float4 v = *(const float4*)(base + (size_t)x * 128 + s0 + 2 * m);
        L[2 * m][x]     = make_float2(v.x, v.y);
        L[2 * m + 1][x] = make_float2(v.z, v.w);
    }
    __syncthreads();
    fft_line(&L[t >> 5][0], t & 31);
    __syncthreads();
#pragma unroll
    for (int i = 0; i < 4; ++i) {
        int n = t + 1024 * i;             // 4096 elems
        int ds = n >> 7, sx = n & 127;
        float2 c = L[ds][sx];
        float pk = c.x * c.x + c.y * c.y;
        int kx = digrev(sx);
        int ky = digrev(s0 + ds);
        int mkx = (kx <= 64) ? kx : 128 - kx;
        int mky = (ky <= 64) ? ky : 128 - ky;
        atomicAdd(&lbins[t & 7][ltab[mkx * 65 + mky]], pk);
    }
    __syncthreads();
    if (t < 101) {
        float wz = (kz == 0 || kz == 64) ? 1.0f : 2.0f;
        float v = lbins[0][t] + lbins[1][t] + lbins[2][t] + lbins[3][t] +
                  lbins[4][t] + lbins[5][t] + lbins[6][t] + lbins[7][t];
        if (v != 0.0f) atomicAdd(&sums[f * 101 + t], v * (NORMF) * wz);
    }
}

// Finalize: Delta^2, log10 ratio, nanmean -> scalar.
__global__ __launch_bounds__(128) void k_finalize(const float* __restrict__ sums,
                                                  const int* __restrict__ counts,
                                                  float* __restrict__ out) {
    __shared__ double ssum[128];
    __shared__ int scnt[128];
    int k = threadIdx.x;
    double local = 0.0;
    int nloc = 0;
    if (k < KBINS) {
        int c = counts[k];
        if (c > 0) {
            double start, step, stop;
            bin_params(&start, &step, &stop);
            double e0 = bin_edge(k, start, step, stop);
            double e1 = bin_edge(k + 1, start, step, stop);
            float kc  = (float)(0.5 * (e0 + e1));
            float kc3 = kc * kc * kc;
            const float two_pi2 = (float)(2.0 * M_PI * M_PI);
            float cf = (float)c;
            for (int b = 0; b < 8; ++b) {
                float pm_p = sums[b * 101 + k] / cf;
                float pm_t = sums[(8 + b) * 101 + k] / cf;
                float dsq_p = pm_p * kc3 / two_pi2;
                float dsq_t = pm_t * kc3 / two_pi2;
                float d = fabsf(log10f(dsq_t) - log10f(dsq_p));
                local += (double)d;
            }
            nloc = 8;
        }
    }
    ssum[k] = local;
    scnt[k] = nloc;
    __syncthreads();
    for (int off = 64; off > 0; off >>= 1) {
        if (k < off) { ssum[k] += ssum[k + off]; scnt[k] += scnt[k + off]; }
        __syncthreads();
    }
    if (k == 0) out[0] = (float)(ssum[0] / (double)scnt[0]);
}

// ---------------- launch ----------------
extern "C" void kernel_launch(void* const* d_in, const int* in_sizes, int n_in,
                              void* d_out, int out_size, void* d_ws, size_t ws_size,
                              hipStream_t stream) {
    (void)in_sizes; (void)n_in; (void)out_size; (void)ws_size;
    const float* pred   = (const float*)d_in[0];
    const float* target = (const float*)d_in[1];
    float* out = (float*)d_out;
    char* ws = (char*)d_ws;

    float* sums        = (float*)(ws + WS_SUMS_OFF);   // [16][101]
    int* counts        = (int*)(ws + WS_CNT_OFF);      // [101]
    unsigned char* oct = (unsigned char*)(ws + WS_OCT_OFF);
    float2* A          = (float2*)(ws + WS_TRANS_OFF); // [16][65][128][128]

    k_zero<<<7, 256, 0, stream>>>(sums, counts);
    k_oct<<<(65 * 65 * 65 + 255) / 256, 256, 0, stream>>>(oct, counts);

    k_fft_z<<<dim3(512, NFIELDS), 1024, 0, stream>>>(pred, target, A);
    k_fft_y<<<dim3(65 * 4, NFIELDS), 1024, 0, stream>>>(A);
    k_fft_x_bin<<<dim3(65 * 4, NFIELDS), 1024, 0, stream>>>(A, oct, sums);

    k_finalize<<<1, 128, 0, stream>>>(sums, counts, out);
}

// Round 7
// 360.628 us; speedup vs baseline: 1.2670x; 1.2670x over previous
//
#include <hip/hip_runtime.h>
#include <math.h>

#ifndef M_PI
#define M_PI 3.14159265358979323846
#endif

// ---------------- constants ----------------
#define NSIDE 128
#define NVOX  2097152          // 128^3
#define KBINS 100
#define NFIELDS 16             // 8 pred + 8 target
#define NORMF (27.0f / 2097152.0f)   // LPIX^3 / N^3
#define FSTRIDE ((size_t)65 * 16384) // float2 elems per field (kz-major planes)

// ws layout (bytes)
#define WS_SUMS_OFF   0                       // float[16*101]
#define WS_CNT_OFF    6464                    // int[101]
#define WS_OCT_OFF    8192                    // uint8[65*65*65], kz-major: oct[c][a][b]
#define WS_TRANS_OFF  282880                  // float2[16 * FSTRIDE] = 136.3 MB

// ---------------- exact numpy binning replication (fp64) ----------------
__device__ __forceinline__ double bin_edge(int i, double start, double step, double stop) {
    if (i == 100) return stop;
    return __dadd_rn(__dmul_rn((double)i, step), start);
}

__device__ __forceinline__ void bin_params(double* start, double* step, double* stop) {
    const double inv   = 1.0 / 384.0;
    const double twopi = 2.0 * M_PI;
    double k1 = __dmul_rn(twopi, __dmul_rn(1.0, inv));
    *start = sqrt(__dadd_rn(__dadd_rn(0.0, 0.0), __dmul_rn(k1, k1)));
    double k64 = __dmul_rn(twopi, __dmul_rn(-64.0, inv));
    double s64 = __dmul_rn(k64, k64);
    *stop = sqrt(__dadd_rn(__dadd_rn(s64, s64), s64));
    *step = (*stop - *start) / 100.0;
}

__device__ int compute_bin(int ix, int iy, int iz) {
    const double inv   = 1.0 / 384.0;
    const double twopi = 2.0 * M_PI;
    double fx = (double)(ix < 64 ? ix : ix - 128);
    double fy = (double)(iy < 64 ? iy : iy - 128);
    double fz = (double)(iz < 64 ? iz : iz - 128);
    double kx = __dmul_rn(twopi, __dmul_rn(fx, inv));
    double ky = __dmul_rn(twopi, __dmul_rn(fy, inv));
    double kz = __dmul_rn(twopi, __dmul_rn(fz, inv));
    double sq = __dadd_rn(__dadd_rn(__dmul_rn(kx, kx), __dmul_rn(ky, ky)), __dmul_rn(kz, kz));
    double kmag = sqrt(sq);
    if (!(kmag > 0.0)) return 100;                   // DC -> dropped bin
    double start, step, stop;
    bin_params(&start, &step, &stop);
    double t = (kmag - start) / step;
    int c = (int)floor(t);
    if (c < -1) c = -1;
    if (c > 100) c = 100;
    while (c < 100 && kmag >= bin_edge(c + 1, start, step, stop)) ++c;
    while (c >= 0 && kmag < bin_edge(c, start, step, stop)) --c;
    if (c < 0) c = 0;
    if (c > 99) c = 99;
    return c;
}

// ---------------- register-resident 128-pt FFT ----------------
// Layout: 32 lanes per line; lane l holds elements {l, l+32, l+64, l+96} in r[0..3].
// Stage 0: radix-4 DIF in registers (stride 32, twiddle W_128^{-l*r}).
// Then each register slot j is an independent 32-pt sub-FFT across lanes:
// 5 radix-2 DIF stages via shfl_xor (mask 16..1, stays within the 32-lane line).
// Final mapping: lane l, reg j holds frequency k = 4*bitrev5(l) + j.

__device__ __forceinline__ int br5(int v) { return (int)(__brev((unsigned)v) >> 27); }

__device__ __forceinline__ float2 cmul(float2 a, float2 w) {
    return make_float2(a.x * w.x - a.y * w.y, a.x * w.y + a.y * w.x);
}
__device__ __forceinline__ float2 twid(float r) {   // e^{2*pi*i*r}, r in revolutions
    return make_float2(__builtin_amdgcn_cosf(r), __builtin_amdgcn_sinf(r));
}

__device__ __forceinline__ void fft128_regs(float2 r[4], int l) {
    // stage 0: radix-4 over register slots (elements l + 32j)
    {
        float2 a0 = r[0], a1 = r[1], a2 = r[2], a3 = r[3];
        float2 s0 = make_float2(a0.x + a2.x, a0.y + a2.y);
        float2 d0 = make_float2(a0.x - a2.x, a0.y - a2.y);
        float2 s1 = make_float2(a1.x + a3.x, a1.y + a3.y);
        float2 d1 = make_float2(a1.x - a3.x, a1.y - a3.y);
        float2 b0 = make_float2(s0.x + s1.x, s0.y + s1.y);
        float2 b2 = make_float2(s0.x - s1.x, s0.y - s1.y);
        float2 b1 = make_float2(d0.x + d1.y, d0.y - d1.x);   // d0 - i*d1
        float2 b3 = make_float2(d0.x - d1.y, d0.y + d1.x);   // d0 + i*d1
        float base = -(float)l * (1.0f / 128.0f);
        float2 w1 = twid(base), w2 = twid(2.0f * base), w3 = twid(3.0f * base);
        r[0] = b0;
        r[1] = cmul(b1, w1);
        r[2] = cmul(b2, w2);
        r[3] = cmul(b3, w3);
    }
    // 5 radix-2 DIF stages across lanes (32-pt sub-FFT per register slot)
#pragma unroll
    for (int h = 16; h >= 1; h >>= 1) {
        bool hi = (l & h) != 0;
        float2 W = twid(-(float)(l & (h - 1)) / (float)(2 * h));
#pragma unroll
        for (int j = 0; j < 4; ++j) {
            float2 x = r[j];
            float2 v = make_float2(__shfl_xor(x.x, h, 64), __shfl_xor(x.y, h, 64));
            float2 sum = make_float2(x.x + v.x, x.y + v.y);
            float2 dif = make_float2(v.x - x.x, v.y - x.y);   // (low - high) seen by hi lane
            float2 tw  = cmul(dif, W);
            r[j] = hi ? tw : sum;
        }
    }
}

// ---------------- kernels ----------------
__global__ __launch_bounds__(256) void k_zero(float* sums, int* counts) {
    int t = blockIdx.x * 256 + threadIdx.x;
    if (t < NFIELDS * 101) sums[t] = 0.0f;
    if (t < 101) counts[t] = 0;
}

// Octant bin table (kz-major: oct[c][a][b]) + exact weighted mode counts.
__global__ __launch_bounds__(256) void k_oct(unsigned char* __restrict__ oct,
                                             int* __restrict__ counts) {
    __shared__ int lcnt[4][104];
    int tid = threadIdx.x;
#pragma unroll
    for (int j = tid; j < 4 * 104; j += 256) ((int*)lcnt)[j] = 0;
    __syncthreads();
    int idx = blockIdx.x * 256 + tid;
    if (idx < 65 * 65 * 65) {
        int c = idx % 65;
        int r = idx / 65;
        int b = r % 65;
        int a = r / 65;
        int id = compute_bin(a, b, c);
        oct[c * 4225 + a * 65 + b] = (unsigned char)id;
        if (id < 100) {
            int w = ((a == 0 || a == 64) ? 1 : 2) *
                    ((b == 0 || b == 64) ? 1 : 2) *
                    ((c == 0 || c == 64) ? 1 : 2);
            atomicAdd(&lcnt[tid & 3][id], w);
        }
    }
    __syncthreads();
    if (tid < 101) {
        int tot = lcnt[0][tid] + lcnt[1][tid] + lcnt[2][tid] + lcnt[3][tid];
        if (tot) atomicAdd(&counts[tid], tot);
    }
}

// Pass Z: FFT along z in registers. Block: fixed x, 32 consecutive y lines.
// LDS used only for the kz-transpose on the store side.
// Writes A[f][kz][x][y], natural kz 0..64.
__global__ __launch_bounds__(1024, 8) void k_fft_z(const float* __restrict__ pred,
                                                   const float* __restrict__ target,
                                                   float2* __restrict__ A) {
    __shared__ float2 L[32][129];
    int t = threadIdx.x;
    int l = t & 31;
    int row = t >> 5;                     // dy = 0..31
    int x  = blockIdx.x >> 2;
    int y0 = (blockIdx.x & 3) << 5;
    int f = blockIdx.y;
    const float* in = (f < 8) ? (pred + (size_t)f * NVOX)
                              : (target + (size_t)(f - 8) * NVOX);
    const float* src = in + (size_t)x * 16384 + (size_t)(y0 + row) * 128;
    float2 r[4];
#pragma unroll
    for (int j = 0; j < 4; ++j) r[j] = make_float2(src[l + 32 * j], 0.0f);
    fft128_regs(r, l);
#pragma unroll
    for (int j = 0; j < 4; ++j) L[row][l + 32 * j] = r[j];   // slot order
    __syncthreads();
    float2* dst = A + (size_t)f * FSTRIDE;
#pragma unroll
    for (int i = 0; i < 3; ++i) {
        int kk = (t >> 5) + 32 * i;       // natural kz
        int dy = t & 31;
        if (kk <= 64) {
            int slot = br5(kk >> 2) + 32 * (kk & 3);   // freq -> (lane,reg) slot
            dst[(size_t)kk * 16384 + (size_t)x * 128 + y0 + dy] = L[dy][slot];
        }
    }
}

// Pass Y: FFT along y fully in registers — NO LDS, NO barriers.
// In-place on 32 x-rows of one plane; output left in slot order along y:
// position p holds frequency 4*br5(p&31) + (p>>5).
__global__ __launch_bounds__(1024, 8) void k_fft_y(float2* __restrict__ A) {
    int t = threadIdx.x;
    int l = t & 31;
    int row = t >> 5;                     // x-row within 32-row tile
    int kz = blockIdx.x >> 2;
    int xg = blockIdx.x & 3;
    int f = blockIdx.y;
    float2* base = A + (size_t)f * FSTRIDE + (size_t)kz * 16384
                     + (size_t)(xg * 32 + row) * 128;
    float2 r[4];
#pragma unroll
    for (int j = 0; j < 4; ++j) r[j] = base[l + 32 * j];
    fft128_regs(r, l);
#pragma unroll
    for (int j = 0; j < 4; ++j) base[l + 32 * j] = r[j];
}

// Pass X: FFT along x in registers + power + radial binning. LDS only for the
// coalesced-load column transpose. Bins accumulated straight from registers.
__global__ __launch_bounds__(1024, 8) void k_fft_x_bin(const float2* __restrict__ A,
                                                       const unsigned char* __restrict__ oct,
                                                       float* __restrict__ sums) {
    __shared__ float2 L[32][129];
    __shared__ float lbins[8][104];
    __shared__ unsigned char ltab[4225];
    int t = threadIdx.x;
    int kz = blockIdx.x >> 2;
    int s0 = (blockIdx.x & 3) << 5;       // y-slot group
    int f = blockIdx.y;
    const float2* base = A + (size_t)f * FSTRIDE + (size_t)kz * 16384;
    for (int j = t; j < 8 * 104; j += 1024) ((float*)lbins)[j] = 0.0f;
    for (int j = t; j < 4225; j += 1024) ltab[j] = oct[kz * 4225 + j];
#pragma unroll
    for (int i = 0; i < 2; ++i) {
        int n = t + 1024 * i;             // 2048 float4
        int x = n >> 4;
        int m = n & 15;
        float4 v = *(const float4*)(base + (size_t)x * 128 + s0 + 2 * m);
        L[2 * m][x]     = make_float2(v.x, v.y);
        L[2 * m + 1][x] = make_float2(v.z, v.w);
    }
    __syncthreads();
    int l = t & 31;
    int yc = t >> 5;                      // y-slot within slab
    float2 r[4];
#pragma unroll
    for (int j = 0; j < 4; ++j) r[j] = L[yc][l + 32 * j];
    fft128_regs(r, l);
    int p = s0 + yc;                      // y slot position in memory
    int ky = 4 * br5(p & 31) + (p >> 5);  // y-pass slot->frequency map
    int mky = (ky <= 64) ? ky : 128 - ky;
#pragma unroll
    for (int j = 0; j < 4; ++j) {
        int kx = 4 * br5(l) + j;
        int mkx = (kx <= 64) ? kx : 128 - kx;
        float2 c = r[j];
        float pk = c.x * c.x + c.y * c.y;
        atomicAdd(&lbins[t & 7][ltab[mkx * 65 + mky]], pk);
    }
    __syncthreads();
    if (t < 101) {
        float wz = (kz == 0 || kz == 64) ? 1.0f : 2.0f;
        float v = lbins[0][t] + lbins[1][t] + lbins[2][t] + lbins[3][t] +
                  lbins[4][t] + lbins[5][t] + lbins[6][t] + lbins[7][t];
        if (v != 0.0f) atomicAdd(&sums[f * 101 + t], v * (NORMF) * wz);
    }
}

// Finalize: Delta^2, log10 ratio, nanmean -> scalar.
__global__ __launch_bounds__(128) void k_finalize(const float* __restrict__ sums,
                                                  const int* __restrict__ counts,
                                                  float* __restrict__ out) {
    __shared__ double ssum[128];
    __shared__ int scnt[128];
    int k = threadIdx.x;
    double local = 0.0;
    int nloc = 0;
    if (k < KBINS) {
        int c = counts[k];
        if (c > 0) {
            double start, step, stop;
            bin_params(&start, &step, &stop);
            double e0 = bin_edge(k, start, step, stop);
            double e1 = bin_edge(k + 1, start, step, stop);
            float kc  = (float)(0.5 * (e0 + e1));
            float kc3 = kc * kc * kc;
            const float two_pi2 = (float)(2.0 * M_PI * M_PI);
            float cf = (float)c;
            for (int b = 0; b < 8; ++b) {
                float pm_p = sums[b * 101 + k] / cf;
                float pm_t = sums[(8 + b) * 101 + k] / cf;
                float dsq_p = pm_p * kc3 / two_pi2;
                float dsq_t = pm_t * kc3 / two_pi2;
                float d = fabsf(log10f(dsq_t) - log10f(dsq_p));
                local += (double)d;
            }
            nloc = 8;
        }
    }
    ssum[k] = local;
    scnt[k] = nloc;
    __syncthreads();
    for (int off = 64; off > 0; off >>= 1) {
        if (k < off) { ssum[k] += ssum[k + off]; scnt[k] += scnt[k + off]; }
        __syncthreads();
    }
    if (k == 0) out[0] = (float)(ssum[0] / (double)scnt[0]);
}

// ---------------- launch ----------------
extern "C" void kernel_launch(void* const* d_in, const int* in_sizes, int n_in,
                              void* d_out, int out_size, void* d_ws, size_t ws_size,
                              hipStream_t stream) {
    (void)in_sizes; (void)n_in; (void)out_size; (void)ws_size;
    const float* pred   = (const float*)d_in[0];
    const float* target = (const float*)d_in[1];
    float* out = (float*)d_out;
    char* ws = (char*)d_ws;

    float* sums        = (float*)(ws + WS_SUMS_OFF);   // [16][101]
    int* counts        = (int*)(ws + WS_CNT_OFF);      // [101]
    unsigned char* oct = (unsigned char*)(ws + WS_OCT_OFF);
    float2* A          = (float2*)(ws + WS_TRANS_OFF); // [16][65][128][128]

    k_zero<<<7, 256, 0, stream>>>(sums, counts);
    k_oct<<<(65 * 65 * 65 + 255) / 256, 256, 0, stream>>>(oct, counts);

    k_fft_z<<<dim3(512, NFIELDS), 1024, 0, stream>>>(pred, target, A);
    k_fft_y<<<dim3(65 * 4, NFIELDS), 1024, 0, stream>>>(A);
    k_fft_x_bin<<<dim3(65 * 4, NFIELDS), 1024, 0, stream>>>(A, oct, sums);

    k_finalize<<<1, 128, 0, stream>>>(sums, counts, out);
}

// Round 8
// 342.311 us; speedup vs baseline: 1.3348x; 1.0535x over previous
//
#include <hip/hip_runtime.h>
#include <math.h>

#ifndef M_PI
#define M_PI 3.14159265358979323846
#endif

// ---------------- constants ----------------
#define NSIDE 128
#define NVOX  2097152          // 128^3
#define KBINS 100
#define NFIELDS 16             // 8 pred + 8 target
#define NORMF (27.0f / 2097152.0f)   // LPIX^3 / N^3
#define FSTRIDE ((size_t)65 * 16384) // float2 elems per field (kz-major planes)

// ws layout (bytes)
#define WS_SUMS_OFF   0                       // float[16*101]
#define WS_CNT_OFF    6464                    // int[101]
#define WS_OCT_OFF    8192                    // uint8[65*65*65], kz-major: oct[c][a][b]
#define WS_TRANS_OFF  282880                  // float2[16 * FSTRIDE] = 136.3 MB

// ---------------- exact numpy binning replication (fp64) ----------------
__device__ __forceinline__ double bin_edge(int i, double start, double step, double stop) {
    if (i == 100) return stop;
    return __dadd_rn(__dmul_rn((double)i, step), start);
}

__device__ __forceinline__ void bin_params(double* start, double* step, double* stop) {
    const double inv   = 1.0 / 384.0;
    const double twopi = 2.0 * M_PI;
    double k1 = __dmul_rn(twopi, __dmul_rn(1.0, inv));
    *start = sqrt(__dadd_rn(__dadd_rn(0.0, 0.0), __dmul_rn(k1, k1)));
    double k64 = __dmul_rn(twopi, __dmul_rn(-64.0, inv));
    double s64 = __dmul_rn(k64, k64);
    *stop = sqrt(__dadd_rn(__dadd_rn(s64, s64), s64));
    *step = (*stop - *start) / 100.0;
}

__device__ int compute_bin(int ix, int iy, int iz) {
    const double inv   = 1.0 / 384.0;
    const double twopi = 2.0 * M_PI;
    double fx = (double)(ix < 64 ? ix : ix - 128);
    double fy = (double)(iy < 64 ? iy : iy - 128);
    double fz = (double)(iz < 64 ? iz : iz - 128);
    double kx = __dmul_rn(twopi, __dmul_rn(fx, inv));
    double ky = __dmul_rn(twopi, __dmul_rn(fy, inv));
    double kz = __dmul_rn(twopi, __dmul_rn(fz, inv));
    double sq = __dadd_rn(__dadd_rn(__dmul_rn(kx, kx), __dmul_rn(ky, ky)), __dmul_rn(kz, kz));
    double kmag = sqrt(sq);
    if (!(kmag > 0.0)) return 100;                   // DC -> dropped bin
    double start, step, stop;
    bin_params(&start, &step, &stop);
    double t = (kmag - start) / step;
    int c = (int)floor(t);
    if (c < -1) c = -1;
    if (c > 100) c = 100;
    while (c < 100 && kmag >= bin_edge(c + 1, start, step, stop)) ++c;
    while (c >= 0 && kmag < bin_edge(c, start, step, stop)) --c;
    if (c < 0) c = 0;
    if (c > 99) c = 99;
    return c;
}

// ---------------- R=16 register-resident 128-pt FFT ----------------
// 8 lanes per line; lane m (=lane&7) holds elements n = m + 8j in r[j], j=0..15.
// Full radix-2 DIF, 7 stages: strides 64/32/16/8 in-register (zero cross-lane),
// strides 4/2/1 via shfl_xor (3 stages). In-place: position n = m+8j ends up
// holding X[bitrev7(n)] -> frequency k = (br3(m)<<4) | br4(j).

__device__ __forceinline__ int br3(int v) { return ((v & 1) << 2) | (v & 2) | ((v >> 2) & 1); }
__device__ __forceinline__ int br4(int v) {
    return ((v & 1) << 3) | ((v & 2) << 1) | ((v & 4) >> 1) | ((v & 8) >> 3);
}

__device__ __forceinline__ float2 f2add(float2 a, float2 b) { return make_float2(a.x + b.x, a.y + b.y); }
__device__ __forceinline__ float2 f2sub(float2 a, float2 b) { return make_float2(a.x - b.x, a.y - b.y); }
__device__ __forceinline__ float2 cmul(float2 a, float2 w) {
    return make_float2(a.x * w.x - a.y * w.y, a.x * w.y + a.y * w.x);
}
__device__ __forceinline__ float2 twid(float r) {   // e^{2*pi*i*r}, r in revolutions
    return make_float2(__builtin_amdgcn_cosf(r), __builtin_amdgcn_sinf(r));
}

__device__ __forceinline__ void fft128_r16(float2 r[16], int m) {
    const float fm = (float)m;
    // h=64: pairs (j, j+8); twiddle -(m+8j)/128
#pragma unroll
    for (int j = 0; j < 8; ++j) {
        float2 W = twid(-(fm + 8.0f * (float)j) * (1.0f / 128.0f));
        float2 a = r[j], b = r[j + 8];
        r[j]     = f2add(a, b);
        r[j + 8] = cmul(f2sub(a, b), W);
    }
    // h=32: pairs (j, j+4) in each half; twiddle -(m+8*(j&3))/64
#pragma unroll
    for (int j = 0; j < 4; ++j) {
        float2 W = twid(-(fm + 8.0f * (float)j) * (1.0f / 64.0f));
#pragma unroll
        for (int half = 0; half < 16; half += 8) {
            float2 a = r[half + j], b = r[half + j + 4];
            r[half + j]     = f2add(a, b);
            r[half + j + 4] = cmul(f2sub(a, b), W);
        }
    }
    // h=16: pairs (j, j+2) per quarter; twiddle -(m+8*(j&1))/32
#pragma unroll
    for (int j = 0; j < 2; ++j) {
        float2 W = twid(-(fm + 8.0f * (float)j) * (1.0f / 32.0f));
#pragma unroll
        for (int q = 0; q < 16; q += 4) {
            float2 a = r[q + j], b = r[q + j + 2];
            r[q + j]     = f2add(a, b);
            r[q + j + 2] = cmul(f2sub(a, b), W);
        }
    }
    // h=8: pairs (j, j+1); twiddle -m/16
    {
        float2 W = twid(-fm * (1.0f / 16.0f));
#pragma unroll
        for (int q = 0; q < 16; q += 2) {
            float2 a = r[q], b = r[q + 1];
            r[q]     = f2add(a, b);
            r[q + 1] = cmul(f2sub(a, b), W);
        }
    }
    // cross-lane h=4,2 (within the 8-lane line group)
#pragma unroll
    for (int h = 4; h >= 2; h >>= 1) {
        bool hi = (m & h) != 0;
        float2 W = twid(-(float)(m & (h - 1)) / (float)(2 * h));
#pragma unroll
        for (int j = 0; j < 16; ++j) {
            float2 x = r[j];
            float2 v = make_float2(__shfl_xor(x.x, h, 64), __shfl_xor(x.y, h, 64));
            float2 s = f2add(x, v);
            float2 d = cmul(f2sub(v, x), W);
            r[j] = hi ? d : s;
        }
    }
    // h=1: no twiddle
    {
        bool hi = (m & 1) != 0;
#pragma unroll
        for (int j = 0; j < 16; ++j) {
            float2 x = r[j];
            float2 v = make_float2(__shfl_xor(x.x, 1, 64), __shfl_xor(x.y, 1, 64));
            r[j] = hi ? f2sub(v, x) : f2add(x, v);
        }
    }
}

// ---------------- kernels ----------------
__global__ __launch_bounds__(256) void k_zero(float* sums, int* counts) {
    int t = blockIdx.x * 256 + threadIdx.x;
    if (t < NFIELDS * 101) sums[t] = 0.0f;
    if (t < 101) counts[t] = 0;
}

// Octant bin table (kz-major: oct[c][a][b]) + exact weighted mode counts.
__global__ __launch_bounds__(256) void k_oct(unsigned char* __restrict__ oct,
                                             int* __restrict__ counts) {
    __shared__ int lcnt[4][104];
    int tid = threadIdx.x;
#pragma unroll
    for (int j = tid; j < 4 * 104; j += 256) ((int*)lcnt)[j] = 0;
    __syncthreads();
    int idx = blockIdx.x * 256 + tid;
    if (idx < 65 * 65 * 65) {
        int c = idx % 65;
        int r = idx / 65;
        int b = r % 65;
        int a = r / 65;
        int id = compute_bin(a, b, c);
        oct[c * 4225 + a * 65 + b] = (unsigned char)id;
        if (id < 100) {
            int w = ((a == 0 || a == 64) ? 1 : 2) *
                    ((b == 0 || b == 64) ? 1 : 2) *
                    ((c == 0 || c == 64) ? 1 : 2);
            atomicAdd(&lcnt[tid & 3][id], w);
        }
    }
    __syncthreads();
    if (tid < 101) {
        int tot = lcnt[0][tid] + lcnt[1][tid] + lcnt[2][tid] + lcnt[3][tid];
        if (tot) atomicAdd(&counts[tid], tot);
    }
}

// Pass Z: FFT along z in registers. Block: 256 thr = 32 z-lines (fixed x,
// 32 consecutive y). NO LDS: the kz<=64 decimation + transpose to A[kz][x][y]
// is done directly in the store pattern (per-m 64B segments stay coalesced).
__global__ __launch_bounds__(256, 6) void k_fft_z(const float* __restrict__ pred,
                                                  const float* __restrict__ target,
                                                  float2* __restrict__ A) {
    int t = threadIdx.x;
    int m = t & 7, row = t >> 3;          // 32 rows (y)
    int x  = blockIdx.x >> 2;
    int y0 = (blockIdx.x & 3) << 5;
    int f = blockIdx.y;
    const float* in = (f < 8) ? (pred + (size_t)f * NVOX)
                              : (target + (size_t)(f - 8) * NVOX);
    const float* src = in + (size_t)x * 16384 + (size_t)(y0 + row) * 128;
    float2 r[16];
#pragma unroll
    for (int j = 0; j < 16; ++j) r[j] = make_float2(src[m + 8 * j], 0.0f);
    fft128_r16(r, m);
    float2* dst = A + (size_t)f * FSTRIDE + (size_t)x * 128 + (y0 + row);
    int b3 = br3(m);                       // kz = 16*b3 + br4(j)
    if (b3 < 4) {
#pragma unroll
        for (int j = 0; j < 16; ++j) {
            int kz = 16 * b3 + br4(j);
            dst[(size_t)kz * 16384] = r[j];
        }
    } else if (b3 == 4) {                  // m==1: only j=0 -> kz=64
        dst[(size_t)64 * 16384] = r[0];
    }
}

// Pass Y: FFT along y fully in registers, in-place. NO LDS, no barriers.
// Output along y left in slot order: position p holds ky=(br3(p&7)<<4)|br4(p>>3).
__global__ __launch_bounds__(256, 6) void k_fft_y(float2* __restrict__ A) {
    int t = threadIdx.x;
    int m = t & 7, g = t >> 3;            // 32 x-rows per block
    int kz = blockIdx.x >> 2;
    int xg = blockIdx.x & 3;
    int f = blockIdx.y;
    float2* base = A + (size_t)f * FSTRIDE + (size_t)kz * 16384
                     + (size_t)(xg * 32 + g) * 128;
    float2 r[16];
#pragma unroll
    for (int j = 0; j < 16; ++j) r[j] = base[m + 8 * j];
    fft128_r16(r, m);
#pragma unroll
    for (int j = 0; j < 16; ++j) base[m + 8 * j] = r[j];
}

// Pass X: FFT along x in registers + power + radial binning. Strided global
// loads are 64B-coalesced per 8-lane group; LDS only for ltab + lbins.
__global__ __launch_bounds__(256, 6) void k_fft_x_bin(const float2* __restrict__ A,
                                                      const unsigned char* __restrict__ oct,
                                                      float* __restrict__ sums) {
    __shared__ float lbins[8][104];
    __shared__ unsigned char ltab[4225];
    int t = threadIdx.x;
    int m = t & 7, g = t >> 3;            // g: y-slot within group of 32
    int kz = blockIdx.x >> 2;
    int s0 = (blockIdx.x & 3) << 5;
    int f = blockIdx.y;
    for (int j = t; j < 8 * 104; j += 256) ((float*)lbins)[j] = 0.0f;
    for (int j = t; j < 4225; j += 256) ltab[j] = oct[kz * 4225 + j];
    const float2* base = A + (size_t)f * FSTRIDE + (size_t)kz * 16384 + (s0 + g);
    float2 r[16];
#pragma unroll
    for (int j = 0; j < 16; ++j) r[j] = base[(size_t)(m + 8 * j) * 128];
    fft128_r16(r, m);
    __syncthreads();                      // ltab + lbins ready
    int p = s0 + g;
    int ky = (br3(p & 7) << 4) | br4(p >> 3);
    int mky = (ky <= 64) ? ky : 128 - ky;
    int b3x = br3(m) << 4;
#pragma unroll
    for (int j = 0; j < 16; ++j) {
        int kx = b3x | br4(j);
        int mkx = (kx <= 64) ? kx : 128 - kx;
        float pk = r[j].x * r[j].x + r[j].y * r[j].y;
        atomicAdd(&lbins[t & 7][ltab[mkx * 65 + mky]], pk);
    }
    __syncthreads();
    if (t < 101) {
        float wz = (kz == 0 || kz == 64) ? 1.0f : 2.0f;
        float v = lbins[0][t] + lbins[1][t] + lbins[2][t] + lbins[3][t] +
                  lbins[4][t] + lbins[5][t] + lbins[6][t] + lbins[7][t];
        if (v != 0.0f) atomicAdd(&sums[f * 101 + t], v * (NORMF) * wz);
    }
}

// Finalize: Delta^2, log10 ratio, nanmean -> scalar.
__global__ __launch_bounds__(128) void k_finalize(const float* __restrict__ sums,
                                                  const int* __restrict__ counts,
                                                  float* __restrict__ out) {
    __shared__ double ssum[128];
    __shared__ int scnt[128];
    int k = threadIdx.x;
    double local = 0.0;
    int nloc = 0;
    if (k < KBINS) {
        int c = counts[k];
        if (c > 0) {
            double start, step, stop;
            bin_params(&start, &step, &stop);
            double e0 = bin_edge(k, start, step, stop);
            double e1 = bin_edge(k + 1, start, step, stop);
            float kc  = (float)(0.5 * (e0 + e1));
            float kc3 = kc * kc * kc;
            const float two_pi2 = (float)(2.0 * M_PI * M_PI);
            float cf = (float)c;
            for (int b = 0; b < 8; ++b) {
                float pm_p = sums[b * 101 + k] / cf;
                float pm_t = sums[(8 + b) * 101 + k] / cf;
                float dsq_p = pm_p * kc3 / two_pi2;
                float dsq_t = pm_t * kc3 / two_pi2;
                float d = fabsf(log10f(dsq_t) - log10f(dsq_p));
                local += (double)d;
            }
            nloc = 8;
        }
    }
    ssum[k] = local;
    scnt[k] = nloc;
    __syncthreads();
    for (int off = 64; off > 0; off >>= 1) {
        if (k < off) { ssum[k] += ssum[k + off]; scnt[k] += scnt[k + off]; }
        __syncthreads();
    }
    if (k == 0) out[0] = (float)(ssum[0] / (double)scnt[0]);
}

// ---------------- launch ----------------
extern "C" void kernel_launch(void* const* d_in, const int* in_sizes, int n_in,
                              void* d_out, int out_size, void* d_ws, size_t ws_size,
                              hipStream_t stream) {
    (void)in_sizes; (void)n_in; (void)out_size; (void)ws_size;
    const float* pred   = (const float*)d_in[0];
    const float* target = (const float*)d_in[1];
    float* out = (float*)d_out;
    char* ws = (char*)d_ws;

    float* sums        = (float*)(ws + WS_SUMS_OFF);   // [16][101]
    int* counts        = (int*)(ws + WS_CNT_OFF);      // [101]
    unsigned char* oct = (unsigned char*)(ws + WS_OCT_OFF);
    float2* A          = (float2*)(ws + WS_TRANS_OFF); // [65][128][128] per field

    k_zero<<<7, 256, 0, stream>>>(sums, counts);
    k_oct<<<(65 * 65 * 65 + 255) / 256, 256, 0, stream>>>(oct, counts);

    k_fft_z<<<dim3(512, NFIELDS), 256, 0, stream>>>(pred, target, A);
    k_fft_y<<<dim3(65 * 4, NFIELDS), 256, 0, stream>>>(A);
    k_fft_x_bin<<<dim3(65 * 4, NFIELDS), 256, 0, stream>>>(A, oct, sums);

    k_finalize<<<1, 128, 0, stream>>>(sums, counts, out);
}